// Round 1
// baseline (90.711 us; speedup 1.0000x reference)
//
#include <hip/hip_runtime.h>
#include <math.h>

// MX-style group quantize-dequantize:
//   groups of 128 contiguous fp32 elements
//   amax = max|x| over group
//   e = clip(ceil(log2(amax) - 7), -128, 127)
//   out = clip(rint(x * 2^-e), -128, 127) * 2^e
//
// Layout: 1 group = 32 lanes x float4. Wave64 holds 2 groups (aligned 32-lane
// halves), so __shfl_xor with masks 1..16 reduces within a group and never
// crosses the group boundary.

constexpr int BLOCK = 256;

__global__ __launch_bounds__(BLOCK) void mx_qdq_kernel(const float* __restrict__ x,
                                                       float* __restrict__ out,
                                                       long long n) {
    long long tid  = (long long)blockIdx.x * BLOCK + threadIdx.x;
    long long base = tid * 4;
    if (base >= n) return;

    const float4 v = *reinterpret_cast<const float4*>(x + base);

    // per-thread abs-max over 4 elements
    float amax = fmaxf(fmaxf(fabsf(v.x), fabsf(v.y)),
                       fmaxf(fabsf(v.z), fabsf(v.w)));

    // reduce across the 32 lanes of this group (masks 1..16 stay inside the
    // aligned 32-lane half of the wave)
    #pragma unroll
    for (int m = 1; m <= 16; m <<= 1)
        amax = fmaxf(amax, __shfl_xor(amax, m));

    // shared exponent (round half-to-even semantics elsewhere don't apply
    // here: ceil after float32 log2, matching the numpy/jax reference)
    float se = ceilf(log2f(amax) - 7.0f);
    se = fminf(fmaxf(se, -128.0f), 127.0f);
    const float scale = exp2f(-se);  // 2^-e
    const float step  = exp2f(se);   // 2^e

    float4 o;
    o.x = fminf(fmaxf(rintf(v.x * scale), -128.0f), 127.0f) * step;
    o.y = fminf(fmaxf(rintf(v.y * scale), -128.0f), 127.0f) * step;
    o.z = fminf(fmaxf(rintf(v.z * scale), -128.0f), 127.0f) * step;
    o.w = fminf(fmaxf(rintf(v.w * scale), -128.0f), 127.0f) * step;

    *reinterpret_cast<float4*>(out + base) = o;
}

extern "C" void kernel_launch(void* const* d_in, const int* in_sizes, int n_in,
                              void* d_out, int out_size, void* d_ws, size_t ws_size,
                              hipStream_t stream) {
    const float* x = (const float*)d_in[0];
    float* out = (float*)d_out;
    long long n = (long long)in_sizes[0];

    long long threads = (n + 3) / 4;
    int blocks = (int)((threads + BLOCK - 1) / BLOCK);
    mx_qdq_kernel<<<blocks, BLOCK, 0, stream>>>(x, out, n);
}

// Round 2
// 84.720 us; speedup vs baseline: 1.0707x; 1.0707x over previous
//
#include <hip/hip_runtime.h>
#include <math.h>

// MX-style group quantize-dequantize:
//   groups of 128 contiguous fp32 elements
//   amax = max|x| over group
//   e = clip(ceil(log2(amax) - 7), -128, 127)
//   out = clip(rint(x * 2^-e), -128, 127) * 2^e
//
// Layout: 1 group = 32 lanes x float4. Wave64 holds 2 groups (aligned 32-lane
// halves), so __shfl_xor with masks 1..16 reduces within a group and never
// crosses the group boundary.
//
// R1 change: non-temporal load/store (streaming data >> 32MB L2; avoid
// write-allocate + cache churn on the pure-streaming paths).

constexpr int BLOCK = 256;

typedef float f32x4 __attribute__((ext_vector_type(4)));

__global__ __launch_bounds__(BLOCK) void mx_qdq_kernel(const float* __restrict__ x,
                                                       float* __restrict__ out,
                                                       long long n) {
    long long tid  = (long long)blockIdx.x * BLOCK + threadIdx.x;
    long long base = tid * 4;
    if (base >= n) return;

    const f32x4 v = __builtin_nontemporal_load(
        reinterpret_cast<const f32x4*>(x + base));

    // per-thread abs-max over 4 elements
    float amax = fmaxf(fmaxf(fabsf(v.x), fabsf(v.y)),
                       fmaxf(fabsf(v.z), fabsf(v.w)));

    // reduce across the 32 lanes of this group (masks 1..16 stay inside the
    // aligned 32-lane half of the wave)
    #pragma unroll
    for (int m = 1; m <= 16; m <<= 1)
        amax = fmaxf(amax, __shfl_xor(amax, m));

    // shared exponent: ceil after float32 log2, matching the numpy/jax ref
    float se = ceilf(log2f(amax) - 7.0f);
    se = fminf(fmaxf(se, -128.0f), 127.0f);
    const float scale = exp2f(-se);  // 2^-e
    const float step  = exp2f(se);   // 2^e

    f32x4 o;
    o.x = fminf(fmaxf(rintf(v.x * scale), -128.0f), 127.0f) * step;
    o.y = fminf(fmaxf(rintf(v.y * scale), -128.0f), 127.0f) * step;
    o.z = fminf(fmaxf(rintf(v.z * scale), -128.0f), 127.0f) * step;
    o.w = fminf(fmaxf(rintf(v.w * scale), -128.0f), 127.0f) * step;

    __builtin_nontemporal_store(o, reinterpret_cast<f32x4*>(out + base));
}

extern "C" void kernel_launch(void* const* d_in, const int* in_sizes, int n_in,
                              void* d_out, int out_size, void* d_ws, size_t ws_size,
                              hipStream_t stream) {
    const float* x = (const float*)d_in[0];
    float* out = (float*)d_out;
    long long n = (long long)in_sizes[0];

    long long threads = (n + 3) / 4;
    int blocks = (int)((threads + BLOCK - 1) / BLOCK);
    mx_qdq_kernel<<<blocks, BLOCK, 0, stream>>>(x, out, n);
}